// Round 6
// baseline (106.604 us; speedup 1.0000x reference)
//
#include <hip/hip_runtime.h>

typedef unsigned short u16;
typedef __attribute__((ext_vector_type(8))) __bf16 bf16x8;
typedef __attribute__((ext_vector_type(8))) unsigned short u16x8;
typedef __attribute__((ext_vector_type(4))) float f32x4;

__device__ __forceinline__ u16 f2bf(float f) {
  unsigned u = __builtin_bit_cast(unsigned, f);
  unsigned r = u + 0x7fffu + ((u >> 16) & 1u);
  return (u16)(r >> 16);
}

__device__ __forceinline__ float wave_sum(float v) {
#pragma unroll
  for (int o = 32; o; o >>= 1) v += __shfl_xor(v, o, 64);
  return v;
}

// async global(16B/lane) -> LDS (wave-uniform dest + lane*16)
__device__ __forceinline__ void gl2lds16(const u16* g, u16* l) {
  __builtin_amdgcn_global_load_lds(
      (const __attribute__((address_space(1))) unsigned int*)(const void*)g,
      (__attribute__((address_space(3))) unsigned int*)(void*)l, 16, 0, 0);
}

// ===== K1: xin build (blocks 0..255) + plane sums (256..1279) =====
// xin layout: [b][h][cg(16)][pxp(66)][ch(32)] bf16; pxp 0 and 65 are ZERO pads,
// pxp = px+1. Per-(b,h) slab = 16*66*32 = 33792 u16.
__global__ void k_xin_plane(const float* __restrict__ tgt, const float* __restrict__ prev,
                            const float* __restrict__ src,
                            u16* __restrict__ xin, float* __restrict__ ssum) {
  int tid = threadIdx.x;
  if (blockIdx.x >= 256) {              // ---- plane sum of source_enc ----
    __shared__ float red[4];
    int plane = blockIdx.x - 256;       // 0..1023
    const float* p = src + (size_t)plane * 4096;
    float s = 0.f;
#pragma unroll
    for (int i = 0; i < 4; ++i) {
      f32x4 v = *(const f32x4*)(p + (i * 256 + tid) * 4);
      s += v[0] + v[1] + v[2] + v[3];
    }
    s = wave_sum(s);
    if ((tid & 63) == 0) red[tid >> 6] = s;
    __syncthreads();
    if (tid == 0) ssum[plane] = red[0] + red[1] + red[2] + red[3];
    return;
  }
  int b = blockIdx.x >> 6, h = blockIdx.x & 63;
  u16* slab = xin + (size_t)(b * 64 + h) * 33792;
  // zero px pads: 16 cg x {0,65} x 32 ch = 1024 u16
  {
    int cc = tid >> 3, e = (tid & 7) * 4;
    int cg = cc >> 1, col = (cc & 1) ? 65 : 0;
    u16* z = slab + (cg * 66 + col) * 32 + e;
    z[0] = 0; z[1] = 0; z[2] = 0; z[3] = 0;
  }
  // target channels 0..255 -> cg 0..7
  for (int it = 0; it < 8; ++it) {
    int i = it * 256 + tid;
    int c8 = i & 31, w = i >> 5;
    const float* tp = tgt + (((size_t)(b * 256 + c8 * 8)) * 64 + h) * 64 + w;
    u16x8 v;
#pragma unroll
    for (int kk = 0; kk < 8; ++kk) v[kk] = f2bf(tp[(size_t)kk * 4096]);
    *(u16x8*)(slab + ((c8 >> 2) * 66 + 1 + w) * 32 + (c8 & 3) * 8) = v;
  }
  // prev channels (2x2 upsample) -> cg 8..15
  for (int it = 0; it < 8; ++it) {
    int i = it * 256 + tid;
    int po = i & 31, w = i >> 5;
    const float* pp = prev + (((size_t)(b * 256 + po * 8)) * 32 + (h >> 1)) * 32 + (w >> 1);
    u16x8 v;
#pragma unroll
    for (int kk = 0; kk < 8; ++kk) v[kk] = f2bf(pp[(size_t)kk * 1024]);
    int cg = 8 + (po >> 2), sub = po & 3;
    *(u16x8*)(slab + (cg * 66 + 1 + w) * 32 + sub * 8) = v;
  }
}

// ===== K2: Mt rows (blocks 0..255, G folded via E=A2@Wk) + dvec chain (block 256) =====
__global__ void k_mt_vec(const float* __restrict__ ssum,
                         const float* __restrict__ qw, const float* __restrict__ qb,
                         const float* __restrict__ kw, const float* __restrict__ kb,
                         const float* __restrict__ lw, const float* __restrict__ lb,
                         const float* __restrict__ aw, const float* __restrict__ ab,
                         const float* __restrict__ gamma,
                         float* __restrict__ dvec, float* __restrict__ Mt) {
  int t = threadIdx.x;
  if (blockIdx.x < 256) {
    __shared__ float E[32];
    int o = blockIdx.x;
    if (t < 32) {
      float s = 0.f;
      for (int o2 = 0; o2 < 32; ++o2) s += aw[o * 288 + 256 + o2] * lw[o2 * 64 + t];
      E[t] = s;
    }
    __syncthreads();
    int c2 = t;
    float s = 0.f;
    for (int a = 0; a < 32; ++a) s += E[a] * kw[a * 256 + c2];
    Mt[o * 256 + c2] = gamma[0] * (aw[o * 288 + c2] + 4096.f * s) + (o == c2 ? 1.f : 0.f);
    return;
  }
  __shared__ float qs_l[128], amap_l[128];
  if (t < 128) {
    int b = t >> 5, o = t & 31;
    float s = 4096.f * qb[o];
    for (int c = 0; c < 256; ++c) s += qw[o * 256 + c] * ssum[b * 256 + c];
    qs_l[t] = s;
  }
  __syncthreads();
  if (t < 128) {
    int b = t >> 5, o2 = t & 31;
    float s = 0.f, kt = 0.f;
    for (int o = 0; o < 32; ++o) {
      s += lw[o2 * 64 + 32 + o] * qs_l[b * 32 + o];
      kt += lw[o2 * 64 + o] * kb[o];
    }
    amap_l[t] = 4096.f * (kt + lb[o2]) + s;
  }
  __syncthreads();
  float g = gamma[0];
  for (int i = t; i < 1024; i += 256) {
    int b = i >> 8, c = i & 255;
    float s = ab[c];
    for (int o2 = 0; o2 < 32; ++o2) s += aw[c * 288 + 256 + o2] * amap_l[b * 32 + o2];
    dvec[i] = g * s;
  }
}

// ===== K3: folded conv weights w3 (bf16, B-fragment-major) + cd2 =====
// region(cg,ocq,t) = ((cg*4+ocq)*9+t)*1024 u16; within region:
//   nf*512 + oct*128 + oc16*8 + j   for oc = ocq*32+nf*16+oc16, ch = cg*32+oct*8+j
__global__ void k_w3(const float* __restrict__ cw, const float* __restrict__ Mt,
                     const float* __restrict__ dvec, u16* __restrict__ w3,
                     float* __restrict__ cd2) {
  __shared__ float cwl[8 * 512];
  __shared__ float part[512];
  int blk = blockIdx.x;                 // 144 = 9*16
  int tap = blk >> 4, ocg = blk & 15;
  int tid = threadIdx.x;                // 512 threads
  for (int e = tid; e < 4096; e += 512) {
    int oc = e >> 9, c = e & 511;
    cwl[e] = cw[(size_t)((ocg * 8 + oc) * 512 + c) * 9 + tap];
  }
  __syncthreads();
  int wv = tid >> 6, l = tid & 63;
  int c2 = l * 4;
  f32x4 acc = {0.f, 0.f, 0.f, 0.f};
  for (int c = 0; c < 256; ++c) {
    float wc = cwl[wv * 512 + c];
    f32x4 m = *(const f32x4*)(Mt + c * 256 + c2);
#pragma unroll
    for (int j = 0; j < 4; ++j) acc[j] += wc * m[j];
  }
  int ocf = ocg * 8 + wv;
  int ocq = ocf >> 5, nf = (ocf >> 4) & 1, oc16 = ocf & 15;
#pragma unroll
  for (int j2 = 0; j2 < 4; ++j2) {
    int cf = c2 + j2;
    w3[(size_t)(((cf >> 5) * 4 + ocq) * 9 + tap) * 1024 + nf * 512 +
       ((cf >> 3) & 3) * 128 + oc16 * 8 + (cf & 7)] = f2bf(acc[j2]);
    cf = 256 + c2 + j2;
    w3[(size_t)(((cf >> 5) * 4 + ocq) * 9 + tap) * 1024 + nf * 512 +
       ((cf >> 3) & 3) * 128 + oc16 * 8 + (cf & 7)] = f2bf(cwl[wv * 512 + cf]);
  }
  {
    int b = tid >> 7, oc = (tid >> 4) & 7, cp = tid & 15;
    float s = 0.f;
#pragma unroll
    for (int i = 0; i < 16; ++i) s += cwl[oc * 512 + cp * 16 + i] * dvec[b * 256 + cp * 16 + i];
    part[tid] = s;
  }
  __syncthreads();
  if (tid < 32) {
    int b = tid >> 3, oc = tid & 7;
    float s = 0.f;
#pragma unroll
    for (int cp = 0; cp < 16; ++cp) s += part[b * 128 + oc * 16 + cp];
    cd2[(size_t)(b * 128 + ocg * 8 + oc) * 9 + tap] = s;
  }
}

// ===== K4: conv, role-swapped MFMA: A = xin(px x ch) from GLOBAL, B = w3(ch x oc) from LDS.
// Block = (b, hp, ocq): M=128 px (2 rows x 64), N=32 oc, K=16 cg. Grid 512.
// 8 waves = 4 kw (K-split, 4 cg each) x 2 pxh (row). acc (4 mf x 2 nf) f32x4 = 32 VGPR.
// LDS: 4 kw-slices x 9 taps x 1024 u16 = 72 KB, staged per round (4 rounds).
__global__ __launch_bounds__(512, 4) void k_conv(const u16* __restrict__ xin,
                                                 const u16* __restrict__ w3,
                                                 const float* __restrict__ cd2,
                                                 float* __restrict__ out) {
  __shared__ u16 ldsB[36864];           // 72 KB
  int bid = blockIdx.x;                 // 512 = 4b * 32hp * 4ocq
  int b = bid >> 7, hp = (bid >> 2) & 31, ocq = bid & 3;
  int tid = threadIdx.x, l = tid & 63, wv = tid >> 6;
  int kw_ = wv >> 1, pxh = wv & 1;
  int h = hp * 2 + pxh;                 // this wave's output row
  int l15 = l & 15, l4 = l >> 4;

  f32x4 acc[4][2];
#pragma unroll
  for (int mf = 0; mf < 4; ++mf)
#pragma unroll
    for (int nf = 0; nf < 2; ++nf) acc[mf][nf] = f32x4{0.f, 0.f, 0.f, 0.f};

  for (int r = 0; r < 4; ++r) {
    // ---- stage 4 kw-slices of w3 (18 KB each) ----
    {
      int skw = wv >> 1;                // this wave fills its own kw slice
      int cg_s = skw * 4 + r;
      const u16* src = w3 + (size_t)((cg_s * 4 + ocq) * 9) * 1024 + ((wv & 1) * 9) * 512 + l * 8;
      u16* dst = ldsB + skw * 9216 + ((wv & 1) * 9) * 512;
#pragma unroll
      for (int i = 0; i < 9; ++i)
        gl2lds16(src + i * 512, dst + i * 512);
    }
    __syncthreads();                    // drain global_load_lds
    int cg = kw_ * 4 + r;
    const u16* xslab = xin + ((size_t)(b * 64) * 16 + cg) * 2112;  // 66*32
#pragma unroll
    for (int dy = 0; dy < 3; ++dy) {
      int grow = h + dy - 1;
      if ((unsigned)grow < 64u) {
        const u16* Arow = xslab + (size_t)grow * 33792;
#pragma unroll
        for (int dx = 0; dx < 3; ++dx) {
          int t = dy * 3 + dx;
          bf16x8 b0 = *(const bf16x8*)(ldsB + kw_ * 9216 + t * 1024 + l * 8);
          bf16x8 b1 = *(const bf16x8*)(ldsB + kw_ * 9216 + t * 1024 + 512 + l * 8);
#pragma unroll
          for (int mf = 0; mf < 4; ++mf) {
            bf16x8 a = *(const bf16x8*)(Arow + (mf * 16 + dx + l15) * 32 + l4 * 8);
            acc[mf][0] = __builtin_amdgcn_mfma_f32_16x16x32_bf16(a, b0, acc[mf][0], 0, 0, 0);
            acc[mf][1] = __builtin_amdgcn_mfma_f32_16x16x32_bf16(a, b1, acc[mf][1], 0, 0, 0);
          }
        }
      }
    }
    __syncthreads();                    // all reads done before next stage
  }

  // ---- 4-way kw reduction via LDS (reuses ldsB: 6 regions x 8 KB = 48 KB) ----
  float* red = (float*)ldsB;
  if (kw_ > 0) {
    int ridx = (kw_ - 1) * 2 + pxh;
#pragma unroll
    for (int mf = 0; mf < 4; ++mf)
#pragma unroll
      for (int nf = 0; nf < 2; ++nf)
        *(f32x4*)(red + ridx * 2048 + (mf * 2 + nf) * 256 + l * 4) = acc[mf][nf];
  }
  __syncthreads();
  if (kw_ > 0) return;
#pragma unroll
  for (int i = 0; i < 3; ++i) {
    int ridx = i * 2 + pxh;
#pragma unroll
    for (int mf = 0; mf < 4; ++mf)
#pragma unroll
      for (int nf = 0; nf < 2; ++nf) {
        f32x4 v = *(const f32x4*)(red + ridx * 2048 + (mf * 2 + nf) * 256 + l * 4);
#pragma unroll
        for (int jj = 0; jj < 4; ++jj) acc[mf][nf][jj] += v[jj];
      }
  }

  // ---- epilogue: border-masked constant correction + store pre-norm y ----
  bool dy0v = (h > 0), dy2v = (h < 63);
#pragma unroll
  for (int nf = 0; nf < 2; ++nf) {
    int oc = ocq * 32 + nf * 16 + l15;
    const float* cd = cd2 + (size_t)(b * 128 + oc) * 9;
    float sAll = 0.f, sL = 0.f, sR = 0.f;
#pragma unroll
    for (int dy = 0; dy < 3; ++dy) {
      bool v = (dy == 1) || (dy == 0 ? dy0v : dy2v);
      if (v) {
        sAll += cd[dy * 3] + cd[dy * 3 + 1] + cd[dy * 3 + 2];
        sL += cd[dy * 3];
        sR += cd[dy * 3 + 2];
      }
    }
#pragma unroll
    for (int mf = 0; mf < 4; ++mf) {
      int px0 = mf * 16 + l4 * 4;
      f32x4 o;
#pragma unroll
      for (int jj = 0; jj < 4; ++jj) {
        int px = px0 + jj;
        o[jj] = acc[mf][nf][jj] + sAll - (px == 0 ? sL : 0.f) - (px == 63 ? sR : 0.f);
      }
      *(f32x4*)(out + ((size_t)(b * 128 + oc)) * 4096 + h * 64 + px0) = o;
    }
  }
}

// ===== K5: in-place instance norm + relu =====
__global__ void k_norm(float* __restrict__ out) {
  int plane = blockIdx.x;               // 512 = 4*128
  float* p = out + (size_t)plane * 4096;
  int t = threadIdx.x;
  f32x4 v[4];
  float s = 0.f, s2 = 0.f;
#pragma unroll
  for (int i = 0; i < 4; ++i) {
    v[i] = *(const f32x4*)(p + (i * 256 + t) * 4);
#pragma unroll
    for (int k = 0; k < 4; ++k) { s += v[i][k]; s2 += v[i][k] * v[i][k]; }
  }
  s = wave_sum(s); s2 = wave_sum(s2);
  __shared__ float rs[4], rs2[4];
  if ((t & 63) == 0) { rs[t >> 6] = s; rs2[t >> 6] = s2; }
  __syncthreads();
  float S = rs[0] + rs[1] + rs[2] + rs[3];
  float S2 = rs2[0] + rs2[1] + rs2[2] + rs2[3];
  float mean = S * (1.f / 4096.f);
  float var = S2 * (1.f / 4096.f) - mean * mean;
  float inv = rsqrtf(var + 1e-5f);
#pragma unroll
  for (int i = 0; i < 4; ++i) {
    f32x4 o;
#pragma unroll
    for (int k = 0; k < 4; ++k) {
      float y = (v[i][k] - mean) * inv;
      o[k] = y > 0.f ? y : 0.f;
    }
    *(f32x4*)(p + (i * 256 + t) * 4) = o;
  }
}

extern "C" void kernel_launch(void* const* d_in, const int* in_sizes, int n_in,
                              void* d_out, int out_size, void* d_ws, size_t ws_size,
                              hipStream_t stream) {
  const float* src    = (const float*)d_in[0];
  const float* tgt    = (const float*)d_in[1];
  const float* prev   = (const float*)d_in[2];
  const float* key_w  = (const float*)d_in[3];
  const float* key_b  = (const float*)d_in[4];
  const float* qry_w  = (const float*)d_in[5];
  const float* qry_b  = (const float*)d_in[6];
  const float* lin_w  = (const float*)d_in[7];
  const float* lin_b  = (const float*)d_in[8];
  const float* attn_w = (const float*)d_in[9];
  const float* attn_b = (const float*)d_in[10];
  const float* gamma  = (const float*)d_in[11];
  const float* conv_w = (const float*)d_in[12];
  // d_in[13] = conv_b: dropped — per-(b,oc) constant cancels under instance norm.

  char* ws = (char*)d_ws;
  size_t off = 0;
  u16*   xin  = (u16*)(ws + off);  off += 17301504;            // 256 slabs * 33792 u16 * 2B (px-padded)
  float* ssum = (float*)(ws + off); off += 4096;               // 4*256
  float* dvec = (float*)(ws + off); off += 4096;               // 4*256
  float* Mt   = (float*)(ws + off); off += 262144;             // 256*256
  float* cd2  = (float*)(ws + off); off += 18432;              // 4*128*9
  u16*   w3   = (u16*)(ws + off);  off += 1179648;             // 16*4*9*1024 u16
  float* out  = (float*)d_out;

  k_xin_plane<<<1280, 256, 0, stream>>>(tgt, prev, src, xin, ssum);
  k_mt_vec<<<257, 256, 0, stream>>>(ssum, qry_w, qry_b, key_w, key_b, lin_w, lin_b,
                                    attn_w, attn_b, gamma, dvec, Mt);
  k_w3<<<144, 512, 0, stream>>>(conv_w, Mt, dvec, w3, cd2);
  k_conv<<<512, 512, 0, stream>>>(xin, w3, cd2, out);
  k_norm<<<512, 256, 0, stream>>>(out);
}

// Round 7
// 97.925 us; speedup vs baseline: 1.0886x; 1.0886x over previous
//
#include <hip/hip_runtime.h>

typedef unsigned short u16;
typedef __attribute__((ext_vector_type(8))) __bf16 bf16x8;
typedef __attribute__((ext_vector_type(8))) unsigned short u16x8;
typedef __attribute__((ext_vector_type(4))) float f32x4;

__device__ __forceinline__ u16 f2bf(float f) {
  unsigned u = __builtin_bit_cast(unsigned, f);
  unsigned r = u + 0x7fffu + ((u >> 16) & 1u);
  return (u16)(r >> 16);
}

__device__ __forceinline__ float wave_sum(float v) {
#pragma unroll
  for (int o = 32; o; o >>= 1) v += __shfl_xor(v, o, 64);
  return v;
}

// async global(16B/lane) -> LDS (wave-uniform dest; lane*16 implicit)
__device__ __forceinline__ void gl2lds16(const u16* g, u16* l) {
  __builtin_amdgcn_global_load_lds(
      (const __attribute__((address_space(1))) unsigned int*)(const void*)g,
      (__attribute__((address_space(3))) unsigned int*)(void*)l, 16, 0, 0);
}

// ===== K1: xin build (0..255) + plane sums (256..1279) + Mt rows (1280..1535) =====
// xin layout: [b][h][cg(16)][pxp(80)][slot(4)][8ch] bf16. pxp=px+1; cols 0,65..79 zero.
// slot s at pxp holds channel-octet g = s ^ ((pxp>>1)&3)  (bank swizzle, R3-proven).
__global__ void k_pre(const float* __restrict__ tgt, const float* __restrict__ prev,
                      const float* __restrict__ src, const float* __restrict__ kw,
                      const float* __restrict__ lw, const float* __restrict__ aw,
                      const float* __restrict__ gamma,
                      u16* __restrict__ xin, float* __restrict__ ssum,
                      float* __restrict__ Mt) {
  __shared__ u16 lt[16896];             // 256*66 u16 (aliased by other branches)
  int tid = threadIdx.x;
  if (blockIdx.x >= 1280) {             // ---- Mt row ----
    float* E = (float*)lt;
    int o = blockIdx.x - 1280;
    if (tid < 32) {
      float s = 0.f;
      for (int o2 = 0; o2 < 32; ++o2) s += aw[o * 288 + 256 + o2] * lw[o2 * 64 + tid];
      E[tid] = s;
    }
    __syncthreads();
    float s = 0.f;
    for (int a = 0; a < 32; ++a) s += E[a] * kw[a * 256 + tid];
    Mt[o * 256 + tid] = gamma[0] * (aw[o * 288 + tid] + 4096.f * s) + (o == tid ? 1.f : 0.f);
    return;
  }
  if (blockIdx.x >= 256) {              // ---- plane sum of source_enc ----
    float* red = (float*)lt;
    int plane = blockIdx.x - 256;
    const float* p = src + (size_t)plane * 4096;
    float s = 0.f;
#pragma unroll
    for (int i = 0; i < 4; ++i) {
      f32x4 v = *(const f32x4*)(p + (i * 256 + tid) * 4);
      s += v[0] + v[1] + v[2] + v[3];
    }
    s = wave_sum(s);
    if ((tid & 63) == 0) red[tid >> 6] = s;
    __syncthreads();
    if (tid == 0) ssum[plane] = red[0] + red[1] + red[2] + red[3];
    return;
  }
  // ---- xin build (coalesced loads -> LDS transpose -> swizzled u16x8 stores) ----
  int b = blockIdx.x >> 6, h = blockIdx.x & 63;
  u16* slab = xin + (size_t)(b * 64 + h) * 40960;
  // zero pads: pxp = 0 and 65..79 for all 16 cg
  for (int i = tid; i < 8192; i += 256) {
    int cg = i >> 9, rest = i & 511;
    int colidx = rest >> 5, e = rest & 31;
    int pxp = (colidx == 0) ? 0 : (64 + colidx);
    slab[cg * 2560 + pxp * 32 + e] = 0;
  }
  // phase A: target -> lt (coalesced f32x4)
  for (int it = 0; it < 16; ++it) {
    int fi = it * 256 + tid;
    int c = fi >> 4, w4 = fi & 15;
    f32x4 v = *(const f32x4*)(tgt + ((size_t)(b * 256 + c) * 64 + h) * 64 + w4 * 4);
    int base = c * 66 + w4 * 4;
    lt[base] = f2bf(v[0]); lt[base + 1] = f2bf(v[1]);
    lt[base + 2] = f2bf(v[2]); lt[base + 3] = f2bf(v[3]);
  }
  __syncthreads();
  for (int it = 0; it < 8; ++it) {      // write cg 0..7
    int i = it * 256 + tid;
    int o = i & 31, w = i >> 5;
    u16x8 v;
#pragma unroll
    for (int k = 0; k < 8; ++k) v[k] = lt[(o * 8 + k) * 66 + w];
    int cg = o >> 2, g = o & 3, pxp = w + 1;
    int slot = g ^ ((pxp >> 1) & 3);
    *(u16x8*)(slab + cg * 2560 + pxp * 32 + slot * 8) = v;
  }
  __syncthreads();
  // phase B: prev (2x2 upsample) -> lt
  for (int it = 0; it < 8; ++it) {
    int pi = it * 256 + tid;
    int cc = pi >> 3, wq = pi & 7;
    f32x4 v = *(const f32x4*)(prev + ((size_t)(b * 256 + cc) * 32 + (h >> 1)) * 32 + wq * 4);
    int base = cc * 66 + wq * 8;
    u16 b0 = f2bf(v[0]), b1 = f2bf(v[1]), b2 = f2bf(v[2]), b3 = f2bf(v[3]);
    lt[base] = b0; lt[base + 1] = b0; lt[base + 2] = b1; lt[base + 3] = b1;
    lt[base + 4] = b2; lt[base + 5] = b2; lt[base + 6] = b3; lt[base + 7] = b3;
  }
  __syncthreads();
  for (int it = 0; it < 8; ++it) {      // write cg 8..15
    int i = it * 256 + tid;
    int o = i & 31, w = i >> 5;
    u16x8 v;
#pragma unroll
    for (int k = 0; k < 8; ++k) v[k] = lt[(o * 8 + k) * 66 + w];
    int cg = 8 + (o >> 2), g = o & 3, pxp = w + 1;
    int slot = g ^ ((pxp >> 1) & 3);
    *(u16x8*)(slab + cg * 2560 + pxp * 32 + slot * 8) = v;
  }
}

// ===== K3: folded conv weights w3 (R3 fragment layout) + cd2; dvec inline =====
// w3 u16 idx = (tap*16+cg)*4096 + kbq*1024 + oc*8 + j, channel cf = cg*32+kbq*8+j
__global__ void k_w3(const float* __restrict__ cw, const float* __restrict__ Mt,
                     const float* __restrict__ ssum,
                     const float* __restrict__ qw, const float* __restrict__ qb,
                     const float* __restrict__ kb, const float* __restrict__ lw,
                     const float* __restrict__ lb, const float* __restrict__ aw,
                     const float* __restrict__ ab, const float* __restrict__ gamma,
                     u16* __restrict__ w3, float* __restrict__ cd2) {
  __shared__ float qs_l[128], amap_l[128], dvec_l[1024];
  __shared__ float cwl[4096];
  __shared__ float part[512];
  int tid = threadIdx.x;                // 512 threads
  // ---- dvec prologue (recomputed per block; tiny) ----
  if (tid < 128) {
    int bb = tid >> 5, o = tid & 31;
    float s = 4096.f * qb[o];
    for (int c = 0; c < 256; ++c) s += qw[o * 256 + c] * ssum[bb * 256 + c];
    qs_l[tid] = s;
  }
  __syncthreads();
  if (tid < 128) {
    int bb = tid >> 5, o2 = tid & 31;
    float s = 0.f, kt = 0.f;
    for (int o = 0; o < 32; ++o) {
      s += lw[o2 * 64 + 32 + o] * qs_l[bb * 32 + o];
      kt += lw[o2 * 64 + o] * kb[o];
    }
    amap_l[tid] = 4096.f * (kt + lb[o2]) + s;
  }
  __syncthreads();
  float g = gamma[0];
  for (int i = tid; i < 1024; i += 512) {
    int bb = i >> 8, c = i & 255;
    float s = ab[c];
    for (int o2 = 0; o2 < 32; ++o2) s += aw[c * 288 + 256 + o2] * amap_l[bb * 32 + o2];
    dvec_l[i] = g * s;
  }
  // ---- stage conv_w slice ----
  int blk = blockIdx.x;                 // 144 = 9*16
  int tap = blk >> 4, ocg = blk & 15;
  for (int e = tid; e < 4096; e += 512) {
    int oc = e >> 9, c = e & 511;
    cwl[e] = cw[(size_t)((ocg * 8 + oc) * 512 + c) * 9 + tap];
  }
  __syncthreads();
  int wv = tid >> 6, l = tid & 63;
  int c2 = l * 4;
  f32x4 acc = {0.f, 0.f, 0.f, 0.f};
  for (int c = 0; c < 256; ++c) {
    float wc = cwl[wv * 512 + c];
    f32x4 m = *(const f32x4*)(Mt + c * 256 + c2);
#pragma unroll
    for (int j = 0; j < 4; ++j) acc[j] += wc * m[j];
  }
  int ocf = ocg * 8 + wv;
#pragma unroll
  for (int j2 = 0; j2 < 4; ++j2) {
    int cf = c2 + j2;
    w3[(tap * 16 + (cf >> 5)) * 4096 + ((cf >> 3) & 3) * 1024 + ocf * 8 + (cf & 7)] = f2bf(acc[j2]);
    cf = 256 + c2 + j2;
    w3[(tap * 16 + (cf >> 5)) * 4096 + ((cf >> 3) & 3) * 1024 + ocf * 8 + (cf & 7)] =
        f2bf(cwl[wv * 512 + (c2 + j2 + 256)]);
  }
  // ---- cd2 ----
  {
    int bb = tid >> 7, oc = (tid >> 4) & 7, cp = tid & 15;
    float s = 0.f;
#pragma unroll
    for (int i = 0; i < 16; ++i) s += cwl[oc * 512 + cp * 16 + i] * dvec_l[bb * 256 + cp * 16 + i];
    part[tid] = s;
  }
  __syncthreads();
  if (tid < 32) {
    int bb = tid >> 3, oc = tid & 7;
    float s = 0.f;
#pragma unroll
    for (int cp = 0; cp < 16; ++cp) s += part[bb * 128 + oc * 16 + cp];
    cd2[(size_t)(bb * 128 + ocg * 8 + oc) * 9 + tap] = s;
  }
}

// ===== K4: conv, m97-shape. block=(b,hp,dy): M=128 oc, N=128 px (2 rows x 64). =====
// 48 k-steps (16 cg x 3 dx) of BK=32; per step per wave: 16 MFMA + 8 ds_read_b128.
// 4 waves = 2 wr(oc-half) x 2 wc(row); acc 4x4 f32x4; NO intra-block K-split.
// dy-partials combined via f32 atomicAdd into pre-zeroed out.
__global__ __launch_bounds__(256, 3) void k_conv(const u16* __restrict__ xin,
                                                 const u16* __restrict__ w3,
                                                 const float* __restrict__ cd2,
                                                 float* __restrict__ out) {
  __shared__ u16 lds[18432];            // 36 KB: w3 2x4096, xin 2x5120 (u16 idx)
  int bid = blockIdx.x;                 // 384
  int lid = (bid & 7) * 48 + (bid >> 3);  // XCD-chunked: same (b,hp) dy-triple on one XCD
  int b = lid / 96, rem = lid % 96;
  int hp = rem / 3, dy = rem % 3;
  int h0 = hp * 2;
  int tid = threadIdx.x, l = tid & 63, wv = tid >> 6;
  int wr = wv & 1, wc = wv >> 1;
  int r = l & 15, kb4 = l >> 4;

  // pre-zero OOR xin rows in both buffers (never staged)
#pragma unroll
  for (int row = 0; row < 2; ++row) {
    if ((unsigned)(h0 + dy - 1 + row) >= 64u) {
      for (int i = tid; i < 2560; i += 256) {
        lds[8192 + row * 2560 + i] = 0;
        lds[8192 + 5120 + row * 2560 + i] = 0;
      }
    }
  }

  auto ISSUE_W3 = [&](int s) {          // stage w3 for step s into buf s&1
    int cg = s / 3, dx = s % 3;
    const u16* base = w3 + (((dy * 3 + dx) * 16 + cg) << 12);
    u16* dst = lds + (s & 1) * 4096;
#pragma unroll
    for (int j = 0; j < 2; ++j) {
      int p = wv + 4 * j;
      gl2lds16(base + p * 512 + l * 8, dst + p * 512);
    }
  };
  auto ISSUE_XIN = [&](int cg) {        // stage 2 rows for cg into buf cg&1
    u16* dst0 = lds + 8192 + (cg & 1) * 5120;
#pragma unroll
    for (int j = 0; j < 3; ++j) {
      int i = wv + 4 * j;
      if (i < 10) {
        int row = i / 5, p = i % 5;
        int grow = h0 + dy - 1 + row;
        if ((unsigned)grow < 64u)
          gl2lds16(xin + ((size_t)(b * 64 + grow) * 16 + cg) * 2560 + p * 512 + l * 8,
                   dst0 + row * 2560 + p * 512);
      }
    }
  };

  f32x4 acc[4][4];
#pragma unroll
  for (int mf = 0; mf < 4; ++mf)
#pragma unroll
    for (int nf = 0; nf < 4; ++nf) acc[mf][nf] = f32x4{0.f, 0.f, 0.f, 0.f};

  ISSUE_W3(0);
  ISSUE_XIN(0);
  __syncthreads();

  for (int cg = 0; cg < 16; ++cg) {
#pragma unroll
    for (int dx = 0; dx < 3; ++dx) {
      int s = cg * 3 + dx;
      if (s < 47) ISSUE_W3(s + 1);
      if (dx == 0 && cg < 15) ISSUE_XIN(cg + 1);
      const u16* wB = lds + (s & 1) * 4096 + kb4 * 1024 + wr * 512;
      const u16* xB = lds + 8192 + (cg & 1) * 5120 + wc * 2560;
      bf16x8 av[4], bv[4];
#pragma unroll
      for (int mf = 0; mf < 4; ++mf) av[mf] = *(const bf16x8*)(wB + mf * 128 + r * 8);
#pragma unroll
      for (int nf = 0; nf < 4; ++nf) {
        int pxp = nf * 16 + r + dx;
        int slot = kb4 ^ ((pxp >> 1) & 3);
        bv[nf] = *(const bf16x8*)(xB + pxp * 32 + slot * 8);
      }
#pragma unroll
      for (int mf = 0; mf < 4; ++mf)
#pragma unroll
        for (int nf = 0; nf < 4; ++nf)
          acc[mf][nf] = __builtin_amdgcn_mfma_f32_16x16x32_bf16(av[mf], bv[nf], acc[mf][nf], 0, 0, 0);
      __syncthreads();
    }
  }

  // ---- epilogue: atomic accumulate (+ border-masked constants), per out-row ----
  int h = h0 + wc;
  if ((unsigned)(h + dy - 1) < 64u) {   // this dy contributes to row h at all
#pragma unroll
    for (int mf = 0; mf < 4; ++mf) {
#pragma unroll
      for (int j = 0; j < 4; ++j) {
        int oc = wr * 64 + mf * 16 + kb4 * 4 + j;
        const float* cd = cd2 + (size_t)(b * 128 + oc) * 9 + dy * 3;
        float c0 = cd[0], c1 = cd[1], c2v = cd[2];
        float sAll = c0 + c1 + c2v;
        float* ob = out + (size_t)(b * 128 + oc) * 4096 + h * 64;
#pragma unroll
        for (int nf = 0; nf < 4; ++nf) {
          int px = nf * 16 + r;
          float corr = sAll - (px == 0 ? c0 : 0.f) - (px == 63 ? c2v : 0.f);
          atomicAdd(ob + px, acc[mf][nf][j] + corr);
        }
      }
    }
  }
}

// ===== K5: in-place instance norm + relu =====
__global__ void k_norm(float* __restrict__ out) {
  int plane = blockIdx.x;               // 512 = 4*128
  float* p = out + (size_t)plane * 4096;
  int t = threadIdx.x;
  f32x4 v[4];
  float s = 0.f, s2 = 0.f;
#pragma unroll
  for (int i = 0; i < 4; ++i) {
    v[i] = *(const f32x4*)(p + (i * 256 + t) * 4);
#pragma unroll
    for (int k = 0; k < 4; ++k) { s += v[i][k]; s2 += v[i][k] * v[i][k]; }
  }
  s = wave_sum(s); s2 = wave_sum(s2);
  __shared__ float rs[4], rs2[4];
  if ((t & 63) == 0) { rs[t >> 6] = s; rs2[t >> 6] = s2; }
  __syncthreads();
  float S = rs[0] + rs[1] + rs[2] + rs[3];
  float S2 = rs2[0] + rs2[1] + rs2[2] + rs2[3];
  float mean = S * (1.f / 4096.f);
  float var = S2 * (1.f / 4096.f) - mean * mean;
  float inv = rsqrtf(var + 1e-5f);
#pragma unroll
  for (int i = 0; i < 4; ++i) {
    f32x4 o;
#pragma unroll
    for (int k = 0; k < 4; ++k) {
      float y = (v[i][k] - mean) * inv;
      o[k] = y > 0.f ? y : 0.f;
    }
    *(f32x4*)(p + (i * 256 + t) * 4) = o;
  }
}

extern "C" void kernel_launch(void* const* d_in, const int* in_sizes, int n_in,
                              void* d_out, int out_size, void* d_ws, size_t ws_size,
                              hipStream_t stream) {
  const float* src    = (const float*)d_in[0];
  const float* tgt    = (const float*)d_in[1];
  const float* prev   = (const float*)d_in[2];
  const float* key_w  = (const float*)d_in[3];
  const float* key_b  = (const float*)d_in[4];
  const float* qry_w  = (const float*)d_in[5];
  const float* qry_b  = (const float*)d_in[6];
  const float* lin_w  = (const float*)d_in[7];
  const float* lin_b  = (const float*)d_in[8];
  const float* attn_w = (const float*)d_in[9];
  const float* attn_b = (const float*)d_in[10];
  const float* gamma  = (const float*)d_in[11];
  const float* conv_w = (const float*)d_in[12];
  // d_in[13] = conv_b: dropped — per-(b,oc) constant cancels under instance norm.

  char* ws = (char*)d_ws;
  size_t off = 0;
  u16*   xin  = (u16*)(ws + off);  off += 20971520;            // 256 slabs * 40960 u16
  float* ssum = (float*)(ws + off); off += 4096;               // 4*256
  float* Mt   = (float*)(ws + off); off += 262144;             // 256*256
  float* cd2  = (float*)(ws + off); off += 18432;              // 4*128*9
  u16*   w3   = (u16*)(ws + off);  off += 1179648;             // 9*16*4096 u16
  float* out  = (float*)d_out;

  hipMemsetAsync(d_out, 0, (size_t)out_size * 4, stream);      // atomics accumulate into zeros
  k_pre<<<1536, 256, 0, stream>>>(tgt, prev, src, key_w, lin_w, attn_w, gamma,
                                  xin, ssum, Mt);
  k_w3<<<144, 512, 0, stream>>>(conv_w, Mt, ssum, qry_w, qry_b, key_b, lin_w, lin_b,
                                attn_w, attn_b, gamma, w3, cd2);
  k_conv<<<384, 256, 0, stream>>>(xin, w3, cd2, out);
  k_norm<<<512, 256, 0, stream>>>(out);
}